// Round 1
// baseline (638.142 us; speedup 1.0000x reference)
//
#include <hip/hip_runtime.h>
#include <hip/hip_bf16.h>
#include <cmath>

// MatchingNet round 4: drop PT entirely.
//  * exp_gemm: MFMA GEMM -> exp -> LDS transpose -> fully-coalesced h8 P stores.
//    Row sums Rv / col sums Cv via shuffle+atomics (unchanged math+guards).
//  * v-updates (v1 with colM, v2) read row-major P in coalesced column-accumulate
//    strip passes (register accumulators + 1 atomicAdd/atomicMax per col per strip).
//    colM uses the bitwise-identical cm expression (p*p)/(Rv_i*Cv_j) as final.
//  * u1 analytic, folded into colpass1 (a_i = C/(Rv_i+e^a) inline). u2 row pass
//    keeps wave-per-row but with manual 7+tail load unroll for full load overlap.
//  * Sinkhorn T=3 as before: u1, v1, u2, v2, u3-in-final. Only (u3,v2) precision
//    matters; intermediate iterates tolerate the cheaper arithmetic.

#define LDIM 3600
#define DDIM 256
#define BDIM 2
#define VS   3604      // per-batch vector stride (floats), 16B-aligned

typedef __attribute__((ext_vector_type(8))) short    bf16x8;
typedef __attribute__((ext_vector_type(4))) float    f32x4;
typedef __attribute__((ext_vector_type(8))) _Float16 h8;
typedef __attribute__((ext_vector_type(4))) _Float16 h4v;

__device__ __forceinline__ short f2bf(float f) {
    unsigned u = __float_as_uint(f);
    u += 0x7fffu + ((u >> 16) & 1u);   // RNE
    return (short)(u >> 16);
}

// ---- input fp32 -> bf16 conversion ----
__global__ __launch_bounds__(256) void convert_kernel(
    const float4* __restrict__ m0, const float4* __restrict__ m1,
    short4* __restrict__ q, short4* __restrict__ r)
{
    int i = blockIdx.x * 256 + threadIdx.x;   // 460800 float4 per tensor
    float4 a = m0[i]; float4 b = m1[i];
    short4 qa, rb;
    qa.x = f2bf(a.x); qa.y = f2bf(a.y); qa.z = f2bf(a.z); qa.w = f2bf(a.w);
    rb.x = f2bf(b.x); rb.y = f2bf(b.y); rb.z = f2bf(b.z); rb.w = f2bf(b.w);
    q[i] = qa; r[i] = rb;
}

// ---- P[i][j]=exp(dot/6553.6) fp16; writes P (coalesced via LDS), Rv, Cv ----
// block = 4 waves (2x2), wave = 64x64 tile = 4x4 MFMA 16x16x32_bf16 tiles.
__global__ __launch_bounds__(256) void exp_gemm_kernel(
    const short* __restrict__ Xb, const short* __restrict__ Yb,
    _Float16* __restrict__ Pout, float* __restrict__ Rv, float* __restrict__ Cv)
{
    __shared__ __align__(16) _Float16 tile[128][136];   // 34.8 KB, stride 272B
    const int batch = blockIdx.z;
    const short* X = Xb + (size_t)batch * LDIM * DDIM;
    const short* Y = Yb + (size_t)batch * LDIM * DDIM;
    _Float16* Pb = Pout + (size_t)batch * LDIM * LDIM;
    float* Rb_ = Rv + batch * VS;
    float* Cb_ = Cv + batch * VS;

    const int wave = threadIdx.x >> 6;
    const int lane = threadIdx.x & 63;
    const int wm = wave >> 1, wn = wave & 1;
    const int bm0 = blockIdx.y * 128 + wm * 64;
    const int bn0 = blockIdx.x * 128 + wn * 64;
    const int l16 = lane & 15, quad = lane >> 4;

    f32x4 acc[4][4];
#pragma unroll
    for (int s = 0; s < 4; s++)
#pragma unroll
        for (int t = 0; t < 4; t++) acc[s][t] = (f32x4){0.f, 0.f, 0.f, 0.f};

    const short* xr[4]; const short* yr[4];
#pragma unroll
    for (int s = 0; s < 4; s++) {
        int r = bm0 + s * 16 + l16; r = r < LDIM ? r : LDIM - 1;
        xr[s] = X + (size_t)r * DDIM;
        int c = bn0 + s * 16 + l16; c = c < LDIM ? c : LDIM - 1;
        yr[s] = Y + (size_t)c * DDIM;
    }
    for (int k0 = 0; k0 < DDIM; k0 += 32) {
        const int kk = k0 + quad * 8;     // A[m=lane&15][k=quad*8+j]
        bf16x8 af[4], bfr[4];
#pragma unroll
        for (int s = 0; s < 4; s++) {
            af[s]  = *(const bf16x8*)(xr[s] + kk);
            bfr[s] = *(const bf16x8*)(yr[s] + kk);
        }
#pragma unroll
        for (int s = 0; s < 4; s++)
#pragma unroll
            for (int t = 0; t < 4; t++)
                acc[s][t] = __builtin_amdgcn_mfma_f32_16x16x32_bf16(af[s], bfr[t], acc[s][t], 0, 0, 0);
    }
    const float inv = 1.0f / 6553.6f;
    float rs[4][4];   // [s][r] partial row sums (cols this lane touches)
#pragma unroll
    for (int s = 0; s < 4; s++)
#pragma unroll
        for (int r = 0; r < 4; r++) rs[s][r] = 0.f;

#pragma unroll
    for (int t = 0; t < 4; t++) {
        const int col = bn0 + t * 16 + l16;     // D: col=lane&15, row=quad*4+reg
        const int lc  = wn * 64 + t * 16 + l16;
        float csum = 0.f;
#pragma unroll
        for (int s = 0; s < 4; s++) {
            const int row0 = bm0 + s * 16 + quad * 4;
            const int lr0  = wm * 64 + s * 16 + quad * 4;
            _Float16 ph[4];
#pragma unroll
            for (int r = 0; r < 4; r++) {
                ph[r] = (_Float16)__expf(acc[s][t][r] * inv);
                tile[lr0 + r][lc] = ph[r];
            }
            if (col < LDIM && row0 < LDIM) {
#pragma unroll
                for (int r = 0; r < 4; r++) {
                    float pf = (float)ph[r];
                    rs[s][r] += pf;
                    csum += pf;
                }
            }
        }
        csum += __shfl_xor(csum, 16, 64);
        csum += __shfl_xor(csum, 32, 64);
        if (quad == 0 && col < LDIM) atomicAdd(Cb_ + col, csum);
    }
    // row sums: reduce over the 16 lanes (l16) of each quad, then atomics
#pragma unroll
    for (int s = 0; s < 4; s++) {
        const int row0 = bm0 + s * 16 + quad * 4;
#pragma unroll
        for (int r = 0; r < 4; r++) {
            float v = rs[s][r];
            v += __shfl_xor(v, 1, 64);
            v += __shfl_xor(v, 2, 64);
            v += __shfl_xor(v, 4, 64);
            v += __shfl_xor(v, 8, 64);
            if (l16 == 0 && row0 < LDIM) atomicAdd(Rb_ + row0 + r, v);
        }
    }
    __syncthreads();
    // coalesced P store: 8 rounds x (16 rows x 16 chunks of 16B)
    const int srow = threadIdx.x >> 4;     // 0..15
    const int schunk = threadIdx.x & 15;   // 16B chunk within the 128-col tile
    const int gcol = blockIdx.x * 128 + schunk * 8;
#pragma unroll
    for (int rd = 0; rd < 8; rd++) {
        const int lr = rd * 16 + srow;
        const int grow = blockIdx.y * 128 + lr;
        if (grow < LDIM && gcol < LDIM)
            *(h8*)(Pb + (size_t)grow * LDIM + gcol) = *(const h8*)&tile[lr][schunk * 8];
    }
}

// ---- column-accumulate strip pass over row-major P (replaces PT row passes) ----
// mode 1 (av==null): a_i computed inline from Rv (analytic u1); also colM + asum.
// mode 2 (av!=null): a_i = av[i]; colsums + asum only.
// Each block: 20 rows x 3600 cols; thread t<450 owns cols [8t, 8t+8).
__global__ __launch_bounds__(512) void colpass_kernel(
    const _Float16* __restrict__ P, const float* __restrict__ Rv,
    const float* __restrict__ av, const float* __restrict__ Cv,
    const float* __restrict__ alpha_p, float* __restrict__ cs,
    float* __restrict__ colM, float* __restrict__ asum)
{
    const int batch = blockIdx.y;
    const int t = threadIdx.x;
    const int r0 = blockIdx.x * 20;
    const float alpha = alpha_p[0];
    const float ea = __expf(alpha);
    const float C = 1.0f / 7200.0f;
    const _Float16* Pb = P + (size_t)batch * LDIM * LDIM;
    const float* Rvb = Rv + batch * VS;
    const bool active = t < 450;
    const int j0 = t * 8;

    float acc[8]  = {0.f,0.f,0.f,0.f,0.f,0.f,0.f,0.f};
    float cmax[8] = {0.f,0.f,0.f,0.f,0.f,0.f,0.f,0.f};
    float cv8[8];
    if (colM && active) {
#pragma unroll
        for (int k = 0; k < 8; k++) cv8[k] = Cv[batch * VS + j0 + k];
    }
    float myasum = 0.f;
#pragma unroll 4
    for (int ri = 0; ri < 20; ri++) {
        const int r = r0 + ri;
        float Rr = 0.f, a;
        if (av) a = av[batch * VS + r];
        else { Rr = Rvb[r]; a = C / (Rr + ea); }
        if (t == 0) myasum += a;
        if (active) {
            h8 hv = *(const h8*)(Pb + (size_t)r * LDIM + j0);
            if (colM) {
#pragma unroll
                for (int k = 0; k < 8; k++) {
                    float p = (float)hv[k];
                    acc[k] += p * a;
                    float cm = (p * p) / (Rr * cv8[k]);   // IDENTICAL expr to final
                    cmax[k] = fmaxf(cmax[k], cm);
                }
            } else {
#pragma unroll
                for (int k = 0; k < 8; k++) {
                    float p = (float)hv[k];
                    acc[k] += p * a;
                }
            }
        }
    }
    if (active) {
#pragma unroll
        for (int k = 0; k < 8; k++) atomicAdd(cs + batch * VS + j0 + k, acc[k]);
        if (colM) {
#pragma unroll
            for (int k = 0; k < 8; k++)
                atomicMax((unsigned int*)(colM + batch * VS + j0 + k),
                          __float_as_uint(cmax[k]));
        }
    }
    if (t == 0) atomicAdd(asum + batch, myasum);
}

// ---- finish a v-update from colsums: bv = exp(v) incl bin entry ----
__global__ __launch_bounds__(256) void vfin_kernel(
    const float* __restrict__ cs, const float* __restrict__ asum,
    const float* __restrict__ av, const float* __restrict__ alpha_p,
    float* __restrict__ bv)
{
    const int j = blockIdx.x * 256 + threadIdx.x, batch = blockIdx.y;
    if (j > LDIM) return;
    const float alpha = alpha_p[0];
    const float norm = -logf(7200.0f);
    const float abin = av ? av[batch * VS + LDIM]
                          : __expf((logf(3600.0f) + norm) - alpha - __logf(3601.0f));
    float u;
    if (j < LDIM) u = norm - __logf(cs[batch * VS + j] + __expf(alpha) * abin);
    else          u = (logf(3600.0f) + norm) - alpha - __logf(asum[batch] + abin);
    bv[batch * VS + j] = __expf(u);
}

// ---- u-update (exp domain), one wave per row of P, loads fully overlapped ----
__global__ __launch_bounds__(256) void skh_kernel(
    const _Float16* __restrict__ mat, const float* __restrict__ vin,
    float* __restrict__ vout, const float* __restrict__ alpha_p)
{
    const int wave = threadIdx.x >> 6, lane = threadIdx.x & 63;
    const int row = blockIdx.x * 4 + wave, batch = blockIdx.y;
    if (row > LDIM) return;
    const float* vi = vin + batch * VS;
    float psum = 0.f;
    if (row < LDIM) {
        const h8* m8 = (const h8*)(mat + ((size_t)batch * LDIM + row) * LDIM);
        const float4* b4 = (const float4*)vi;
        h8 hv[7];
#pragma unroll
        for (int u = 0; u < 7; u++) hv[u] = m8[lane + 64 * u];   // 450 = 7*64 + 2
        h8 hv7;
        const bool tail = lane < 2;
        if (tail) hv7 = m8[lane + 448];
#pragma unroll
        for (int u = 0; u < 7; u++) {
            const int jv = lane + 64 * u;
            float4 b0 = b4[2 * jv], b1 = b4[2 * jv + 1];
            psum += (float)hv[u][0] * b0.x + (float)hv[u][1] * b0.y
                  + (float)hv[u][2] * b0.z + (float)hv[u][3] * b0.w
                  + (float)hv[u][4] * b1.x + (float)hv[u][5] * b1.y
                  + (float)hv[u][6] * b1.z + (float)hv[u][7] * b1.w;
        }
        if (tail) {
            const int jv = lane + 448;
            float4 b0 = b4[2 * jv], b1 = b4[2 * jv + 1];
            psum += (float)hv7[0] * b0.x + (float)hv7[1] * b0.y
                  + (float)hv7[2] * b0.z + (float)hv7[3] * b0.w
                  + (float)hv7[4] * b1.x + (float)hv7[5] * b1.y
                  + (float)hv7[6] * b1.z + (float)hv7[7] * b1.w;
        }
    } else {
        const float4* b4 = (const float4*)vi;
        for (int jv = lane; jv < 900; jv += 64) {
            float4 b0 = b4[jv];
            psum += (b0.x + b0.y) + (b0.z + b0.w);
        }
        if (lane == 0) psum += vi[LDIM];
    }
#pragma unroll
    for (int off = 32; off; off >>= 1) psum += __shfl_down(psum, off, 64);
    if (lane == 0) {
        const float alpha = alpha_p[0];
        const float norm = -logf(7200.0f);
        float u;
        if (row < LDIM) u = norm - __logf(psum + __expf(alpha) * vi[LDIM]);
        else            u = (logf(3600.0f) + norm) - alpha - __logf(psum);
        vout[batch * VS + row] = __expf(u);
    }
}

// ---- fused epilogue: final u-update + rowM + cm/cf/skh planes. Block per row. ----
__global__ __launch_bounds__(256) void final_kernel(
    const _Float16* __restrict__ P, const float* __restrict__ bv,
    const float* __restrict__ Rvec, const float* __restrict__ Cvec,
    const float* __restrict__ colM, const float* __restrict__ alpha_p,
    float* __restrict__ out)
{
    const int batch = blockIdx.y, row = blockIdx.x, tid = threadIdx.x;
    const h4v* prow = (const h4v*)(P + ((size_t)batch * LDIM + row) * LDIM);
    const float4* b4 = (const float4*)(bv + batch * VS);
    const float4* c4 = (const float4*)(Cvec + batch * VS);
    const float4* m4 = (const float4*)(colM + batch * VS);
    const float Rr = Rvec[batch * VS + row];

    // phase 1: row reduction -> psum (for u), pmax (rowM)
    float psum = 0.f, pmax = 0.f;
    for (int jv = tid; jv < 900; jv += 256) {
        h4v hv = prow[jv]; float4 b = b4[jv]; float4 c = c4[jv];
        float p0 = (float)hv[0], p1 = (float)hv[1], p2 = (float)hv[2], p3 = (float)hv[3];
        psum += p0 * b.x + p1 * b.y + p2 * b.z + p3 * b.w;
        pmax = fmaxf(pmax, (p0 * p0) / (Rr * c.x));
        pmax = fmaxf(pmax, (p1 * p1) / (Rr * c.y));
        pmax = fmaxf(pmax, (p2 * p2) / (Rr * c.z));
        pmax = fmaxf(pmax, (p3 * p3) / (Rr * c.w));
    }
    __shared__ float red_s[256], red_m[256];
    red_s[tid] = psum; red_m[tid] = pmax; __syncthreads();
    for (int w = 128; w; w >>= 1) {
        if (tid < w) {
            red_s[tid] += red_s[tid + w];
            red_m[tid] = fmaxf(red_m[tid], red_m[tid + w]);
        }
        __syncthreads();
    }
    __shared__ float s_as, s_rM;
    if (tid == 0) {
        const float alpha = alpha_p[0];
        const float norm = -logf(7200.0f);
        float u = norm - __logf(red_s[0] + __expf(alpha) * bv[batch * VS + LDIM]);
        s_as = __expf(u) * 7200.0f;
        s_rM = red_m[0];
    }
    __syncthreads();
    const float as = s_as, rM = s_rM;

    // phase 2: outputs (row data hot in L1)
    const size_t PLANE = (size_t)BDIM * LDIM * LDIM;
    const size_t base = ((size_t)batch * LDIM + row) * LDIM;
    for (int jv = tid; jv < 900; jv += 256) {
        h4v hv = prow[jv]; float4 b = b4[jv]; float4 c = c4[jv]; float4 cM = m4[jv];
        float4 cmv, cfv, skv;
        {
            float p = (float)hv[0]; float cm = (p * p) / (Rr * c.x);
            cmv.x = cm; cfv.x = (cm == rM && cm == cM.x) ? cm : 0.f; skv.x = p * as * b.x;
        }
        {
            float p = (float)hv[1]; float cm = (p * p) / (Rr * c.y);
            cmv.y = cm; cfv.y = (cm == rM && cm == cM.y) ? cm : 0.f; skv.y = p * as * b.y;
        }
        {
            float p = (float)hv[2]; float cm = (p * p) / (Rr * c.z);
            cmv.z = cm; cfv.z = (cm == rM && cm == cM.z) ? cm : 0.f; skv.z = p * as * b.z;
        }
        {
            float p = (float)hv[3]; float cm = (p * p) / (Rr * c.w);
            cmv.w = cm; cfv.w = (cm == rM && cm == cM.w) ? cm : 0.f; skv.w = p * as * b.w;
        }
        *(float4*)(out + base + jv * 4) = cmv;
        *(float4*)(out + PLANE + base + jv * 4) = cfv;
        *(float4*)(out + 2 * PLANE + base + jv * 4) = skv;
    }
}

extern "C" void kernel_launch(void* const* d_in, const int* in_sizes, int n_in,
                              void* d_out, int out_size, void* d_ws, size_t ws_size,
                              hipStream_t stream)
{
    const float* m0 = (const float*)d_in[0];
    const float* m1 = (const float*)d_in[1];
    const float* alpha = (const float*)d_in[2];
    float* out = (float*)d_out;
    char* ws = (char*)d_ws;

    // ws layout (bytes), all 16B-aligned; total ~59.4 MB
    short* Qb = (short*)(ws);                         //  3,686,400  bf16 mdesc0
    short* Rb = (short*)(ws + 3686400);               //  3,686,400  bf16 mdesc1
    _Float16* P = (_Float16*)(ws + 7372800);          // 51,840,000  exp(sim)
    float* vec = (float*)(ws + 59212800);             // vectors, stride VS per batch
    float* Rv   = vec;                                // row sums of P     [2*VS]
    float* Cv   = vec + 2 * VS;                       // col sums of P     [2*VS]
    float* cs1  = vec + 4 * VS;                       // v1 weighted colsums
    float* cs2  = vec + 6 * VS;                       // v2 weighted colsums
    float* colM = vec + 8 * VS;                       // colwise max of cm
    float* asum = vec + 10 * VS;                      // [0..1]=v1 a-sums, [2..3]=v2
    float* bv   = vec + 10 * VS + 16;                 // exp(v)            [2*VS]
    float* av   = vec + 12 * VS + 16;                 // exp(u)            [2*VS]

    // zero Rv, Cv, cs1, cs2, colM, asum in one shot
    hipMemsetAsync(vec, 0, (10 * VS + 16) * sizeof(float), stream);
    convert_kernel<<<1800, 256, 0, stream>>>((const float4*)m0, (const float4*)m1,
                                             (short4*)Qb, (short4*)Rb);
    exp_gemm_kernel<<<dim3(29, 29, 2), 256, 0, stream>>>(Qb, Rb, P, Rv, Cv);

    // Sinkhorn T=3 (exp domain): u1 inline-in-colpass1; v1(+colM); u2; v2; u3 in final.
    colpass_kernel<<<dim3(180, 2), 512, 0, stream>>>(P, Rv, nullptr, Cv, alpha,
                                                     cs1, colM, asum);
    vfin_kernel<<<dim3(15, 2), 256, 0, stream>>>(cs1, asum, nullptr, alpha, bv);
    skh_kernel<<<dim3(901, 2), 256, 0, stream>>>(P, bv, av, alpha);
    colpass_kernel<<<dim3(180, 2), 512, 0, stream>>>(P, Rv, av, nullptr, alpha,
                                                     cs2, nullptr, asum + 2);
    vfin_kernel<<<dim3(15, 2), 256, 0, stream>>>(cs2, asum + 2, av, alpha, bv);

    final_kernel<<<dim3(3600, 2), 256, 0, stream>>>(P, bv, Rv, Cv, colM, alpha, out);
}

// Round 2
// 496.508 us; speedup vs baseline: 1.2853x; 1.2853x over previous
//
#include <hip/hip_runtime.h>
#include <hip/hip_bf16.h>
#include <cmath>

// MatchingNet round 5: round-3 structure (known 485us) + unrolled skh loads.
//  * P = exp(sim) in [0.986,1.014] (fp16, + transposed copy PT) from ONE MFMA GEMM
//    that also emits row sums Rv and col sums Cv via shuffle+atomics.
//  * Sinkhorn in exp domain, T=3 (u1 analytic, v1+colM, u2, v2, u3-in-final).
//  * skh_kernel: manual 7+tail load unroll (450 = 7*64 + 2) so all row loads are
//    in flight before first use; accumulation order bit-identical to round 3.
//  * cm tie consistency: identical IEEE expression everywhere; colM pass computes
//    the product commuted (bitwise-equal for fp multiply).

#define LDIM 3600
#define DDIM 256
#define BDIM 2
#define VS   3604      // per-batch vector stride (floats), 16B-aligned

typedef __attribute__((ext_vector_type(8))) short    bf16x8;
typedef __attribute__((ext_vector_type(4))) float    f32x4;
typedef __attribute__((ext_vector_type(8))) _Float16 h8;
typedef __attribute__((ext_vector_type(4))) _Float16 h4v;

__device__ __forceinline__ short f2bf(float f) {
    unsigned u = __float_as_uint(f);
    u += 0x7fffu + ((u >> 16) & 1u);   // RNE
    return (short)(u >> 16);
}

// ---- input fp32 -> bf16 conversion ----
__global__ __launch_bounds__(256) void convert_kernel(
    const float4* __restrict__ m0, const float4* __restrict__ m1,
    short4* __restrict__ q, short4* __restrict__ r)
{
    int i = blockIdx.x * 256 + threadIdx.x;   // 460800 float4 per tensor
    float4 a = m0[i]; float4 b = m1[i];
    short4 qa, rb;
    qa.x = f2bf(a.x); qa.y = f2bf(a.y); qa.z = f2bf(a.z); qa.w = f2bf(a.w);
    rb.x = f2bf(b.x); rb.y = f2bf(b.y); rb.z = f2bf(b.z); rb.w = f2bf(b.w);
    q[i] = qa; r[i] = rb;
}

// ---- P[i][j]=exp(dot/6553.6) fp16; writes P, PT, row sums Rv, col sums Cv ----
// block = 4 waves (2x2), wave = 64x64 tile = 4x4 MFMA 16x16x32_bf16 tiles.
__global__ __launch_bounds__(256) void exp_gemm_kernel(
    const short* __restrict__ Xb, const short* __restrict__ Yb,
    _Float16* __restrict__ Pout, _Float16* __restrict__ PTout,
    float* __restrict__ Rv, float* __restrict__ Cv)
{
    const int batch = blockIdx.z;
    const short* X = Xb + (size_t)batch * LDIM * DDIM;
    const short* Y = Yb + (size_t)batch * LDIM * DDIM;
    _Float16* Pb  = Pout  + (size_t)batch * LDIM * LDIM;
    _Float16* PTb = PTout + (size_t)batch * LDIM * LDIM;
    float* Rb_ = Rv + batch * VS;
    float* Cb_ = Cv + batch * VS;

    const int wave = threadIdx.x >> 6;
    const int lane = threadIdx.x & 63;
    const int wm = wave >> 1, wn = wave & 1;
    const int bm0 = blockIdx.y * 128 + wm * 64;
    const int bn0 = blockIdx.x * 128 + wn * 64;
    const int l16 = lane & 15, quad = lane >> 4;

    f32x4 acc[4][4];
#pragma unroll
    for (int s = 0; s < 4; s++)
#pragma unroll
        for (int t = 0; t < 4; t++) acc[s][t] = (f32x4){0.f, 0.f, 0.f, 0.f};

    const short* xr[4]; const short* yr[4];
#pragma unroll
    for (int s = 0; s < 4; s++) {
        int r = bm0 + s * 16 + l16; r = r < LDIM ? r : LDIM - 1;
        xr[s] = X + (size_t)r * DDIM;
        int c = bn0 + s * 16 + l16; c = c < LDIM ? c : LDIM - 1;
        yr[s] = Y + (size_t)c * DDIM;
    }
    for (int k0 = 0; k0 < DDIM; k0 += 32) {
        const int kk = k0 + quad * 8;     // A[m=lane&15][k=quad*8+j]
        bf16x8 af[4], bfr[4];
#pragma unroll
        for (int s = 0; s < 4; s++) {
            af[s]  = *(const bf16x8*)(xr[s] + kk);
            bfr[s] = *(const bf16x8*)(yr[s] + kk);
        }
#pragma unroll
        for (int s = 0; s < 4; s++)
#pragma unroll
            for (int t = 0; t < 4; t++)
                acc[s][t] = __builtin_amdgcn_mfma_f32_16x16x32_bf16(af[s], bfr[t], acc[s][t], 0, 0, 0);
    }
    const float inv = 1.0f / 6553.6f;
    float rs[4][4];   // [s][r] partial row sums (cols this lane touches)
#pragma unroll
    for (int s = 0; s < 4; s++)
#pragma unroll
        for (int r = 0; r < 4; r++) rs[s][r] = 0.f;

#pragma unroll
    for (int t = 0; t < 4; t++) {
        const int col = bn0 + t * 16 + l16;     // D: col=lane&15, row=quad*4+reg
        float csum = 0.f;
#pragma unroll
        for (int s = 0; s < 4; s++) {
            const int row0 = bm0 + s * 16 + quad * 4;
            h4v ph;
#pragma unroll
            for (int r = 0; r < 4; r++) ph[r] = (_Float16)__expf(acc[s][t][r] * inv);
            if (col < LDIM && row0 < LDIM) {
                *(h4v*)(PTb + (size_t)col * LDIM + row0) = ph;
#pragma unroll
                for (int r = 0; r < 4; r++) {
                    Pb[(size_t)(row0 + r) * LDIM + col] = ph[r];
                    float pf = (float)ph[r];
                    rs[s][r] += pf;
                    csum += pf;
                }
            }
        }
        csum += __shfl_xor(csum, 16, 64);
        csum += __shfl_xor(csum, 32, 64);
        if (quad == 0 && col < LDIM) atomicAdd(Cb_ + col, csum);
    }
    // row sums: reduce over the 16 lanes (l16) of each quad, then atomics
#pragma unroll
    for (int s = 0; s < 4; s++) {
        const int row0 = bm0 + s * 16 + quad * 4;
#pragma unroll
        for (int r = 0; r < 4; r++) {
            float v = rs[s][r];
            v += __shfl_xor(v, 1, 64);
            v += __shfl_xor(v, 2, 64);
            v += __shfl_xor(v, 4, 64);
            v += __shfl_xor(v, 8, 64);
            if (l16 == 0 && row0 < LDIM) atomicAdd(Rb_ + row0 + r, v);
        }
    }
}

// ---- u1 = norm - log(Rv + e^alpha) (b==1 analytic first half-iteration) ----
__global__ __launch_bounds__(256) void u1_kernel(
    const float* __restrict__ Rv, float* __restrict__ av,
    const float* __restrict__ alpha_p)
{
    const int i = blockIdx.x * 256 + threadIdx.x, batch = blockIdx.y;
    if (i > LDIM) return;
    const float alpha = alpha_p[0];
    const float norm = -logf(7200.0f);
    float u;
    if (i < LDIM) u = norm - __logf(Rv[batch * VS + i] + __expf(alpha));
    else          u = (logf(3600.0f) + norm) - alpha - __logf(3601.0f);
    av[batch * VS + i] = __expf(u);
}

// ---- one Sinkhorn half-update (exp domain), one wave per row. ----
// mscal!=null: also per-row max of cm = p*p/(mscal[row]*mvec[j]) -> mout
// Loads manually unrolled 7+tail (450 = 7*64 + 2) for full overlap.
__global__ __launch_bounds__(256) void skh_kernel(
    const _Float16* __restrict__ mat, const float* __restrict__ vin,
    float* __restrict__ vout, const float* __restrict__ alpha_p,
    const float* __restrict__ mscal, const float* __restrict__ mvec,
    float* __restrict__ mout)
{
    const int wave = threadIdx.x >> 6, lane = threadIdx.x & 63;
    const int row = blockIdx.x * 4 + wave, batch = blockIdx.y;
    if (row > LDIM) return;
    const float* vi = vin + batch * VS;
    float psum = 0.f, pmax = 0.f;
    if (row < LDIM) {
        const h8* m8 = (const h8*)(mat + ((size_t)batch * LDIM + row) * LDIM);
        const float4* b4 = (const float4*)vi;
        const float Rr = mscal ? mscal[batch * VS + row] : 0.f;
        const float4* c4 = mscal ? (const float4*)(mvec + batch * VS) : b4;

        h8 hv[7];
#pragma unroll
        for (int u = 0; u < 7; u++) hv[u] = m8[lane + 64 * u];
        h8 hv7;
        const bool tail = lane < 2;
        if (tail) hv7 = m8[lane + 448];

#pragma unroll
        for (int u = 0; u < 7; u++) {
            const int jv = lane + 64 * u;
            float p0 = (float)hv[u][0], p1 = (float)hv[u][1], p2 = (float)hv[u][2], p3 = (float)hv[u][3];
            float p4 = (float)hv[u][4], p5 = (float)hv[u][5], p6 = (float)hv[u][6], p7 = (float)hv[u][7];
            float4 b0 = b4[2 * jv], b1 = b4[2 * jv + 1];
            psum += p0 * b0.x + p1 * b0.y + p2 * b0.z + p3 * b0.w;
            psum += p4 * b1.x + p5 * b1.y + p6 * b1.z + p7 * b1.w;
            if (mscal) {
                float4 c0 = c4[2 * jv], c1 = c4[2 * jv + 1];
                pmax = fmaxf(pmax, (p0 * p0) / (Rr * c0.x));
                pmax = fmaxf(pmax, (p1 * p1) / (Rr * c0.y));
                pmax = fmaxf(pmax, (p2 * p2) / (Rr * c0.z));
                pmax = fmaxf(pmax, (p3 * p3) / (Rr * c0.w));
                pmax = fmaxf(pmax, (p4 * p4) / (Rr * c1.x));
                pmax = fmaxf(pmax, (p5 * p5) / (Rr * c1.y));
                pmax = fmaxf(pmax, (p6 * p6) / (Rr * c1.z));
                pmax = fmaxf(pmax, (p7 * p7) / (Rr * c1.w));
            }
        }
        if (tail) {
            const int jv = lane + 448;
            float p0 = (float)hv7[0], p1 = (float)hv7[1], p2 = (float)hv7[2], p3 = (float)hv7[3];
            float p4 = (float)hv7[4], p5 = (float)hv7[5], p6 = (float)hv7[6], p7 = (float)hv7[7];
            float4 b0 = b4[2 * jv], b1 = b4[2 * jv + 1];
            psum += p0 * b0.x + p1 * b0.y + p2 * b0.z + p3 * b0.w;
            psum += p4 * b1.x + p5 * b1.y + p6 * b1.z + p7 * b1.w;
            if (mscal) {
                float4 c0 = c4[2 * jv], c1 = c4[2 * jv + 1];
                pmax = fmaxf(pmax, (p0 * p0) / (Rr * c0.x));
                pmax = fmaxf(pmax, (p1 * p1) / (Rr * c0.y));
                pmax = fmaxf(pmax, (p2 * p2) / (Rr * c0.z));
                pmax = fmaxf(pmax, (p3 * p3) / (Rr * c0.w));
                pmax = fmaxf(pmax, (p4 * p4) / (Rr * c1.x));
                pmax = fmaxf(pmax, (p5 * p5) / (Rr * c1.y));
                pmax = fmaxf(pmax, (p6 * p6) / (Rr * c1.z));
                pmax = fmaxf(pmax, (p7 * p7) / (Rr * c1.w));
            }
        }
    } else {
        const float4* b4 = (const float4*)vi;
        for (int jv = lane; jv < 900; jv += 64) {
            float4 b0 = b4[jv];
            psum += (b0.x + b0.y) + (b0.z + b0.w);
        }
        if (lane == 0) psum += vi[LDIM];
    }
#pragma unroll
    for (int off = 32; off; off >>= 1) {
        psum += __shfl_down(psum, off, 64);
        pmax = fmaxf(pmax, __shfl_down(pmax, off, 64));
    }
    if (lane == 0) {
        const float alpha = alpha_p[0];
        const float norm = -logf(7200.0f);
        float u;
        if (row < LDIM) {
            if (mout) mout[batch * VS + row] = pmax;
            u = norm - __logf(psum + __expf(alpha) * vi[LDIM]);
        } else {
            u = (logf(3600.0f) + norm) - alpha - __logf(psum);
        }
        vout[batch * VS + row] = __expf(u);
    }
}

// ---- fused epilogue: final u-update + rowM + cm/cf/skh planes. Block per row. ----
__global__ __launch_bounds__(256) void final_kernel(
    const _Float16* __restrict__ P, const float* __restrict__ bv,
    const float* __restrict__ Rvec, const float* __restrict__ Cvec,
    const float* __restrict__ colM, const float* __restrict__ alpha_p,
    float* __restrict__ out)
{
    const int batch = blockIdx.y, row = blockIdx.x, tid = threadIdx.x;
    const h4v* prow = (const h4v*)(P + ((size_t)batch * LDIM + row) * LDIM);
    const float4* b4 = (const float4*)(bv + batch * VS);
    const float4* c4 = (const float4*)(Cvec + batch * VS);
    const float4* m4 = (const float4*)(colM + batch * VS);
    const float Rr = Rvec[batch * VS + row];

    // phase 1: row reduction -> psum (for u), pmax (rowM)
    float psum = 0.f, pmax = 0.f;
    for (int jv = tid; jv < 900; jv += 256) {
        h4v hv = prow[jv]; float4 b = b4[jv]; float4 c = c4[jv];
        float p0 = (float)hv[0], p1 = (float)hv[1], p2 = (float)hv[2], p3 = (float)hv[3];
        psum += p0 * b.x + p1 * b.y + p2 * b.z + p3 * b.w;
        pmax = fmaxf(pmax, (p0 * p0) / (Rr * c.x));
        pmax = fmaxf(pmax, (p1 * p1) / (Rr * c.y));
        pmax = fmaxf(pmax, (p2 * p2) / (Rr * c.z));
        pmax = fmaxf(pmax, (p3 * p3) / (Rr * c.w));
    }
    __shared__ float red_s[256], red_m[256];
    red_s[tid] = psum; red_m[tid] = pmax; __syncthreads();
    for (int w = 128; w; w >>= 1) {
        if (tid < w) {
            red_s[tid] += red_s[tid + w];
            red_m[tid] = fmaxf(red_m[tid], red_m[tid + w]);
        }
        __syncthreads();
    }
    __shared__ float s_as, s_rM;
    if (tid == 0) {
        const float alpha = alpha_p[0];
        const float norm = -logf(7200.0f);
        float u = norm - __logf(red_s[0] + __expf(alpha) * bv[batch * VS + LDIM]);
        s_as = __expf(u) * 7200.0f;
        s_rM = red_m[0];
    }
    __syncthreads();
    const float as = s_as, rM = s_rM;

    // phase 2: outputs (row data hot in L1)
    const size_t PLANE = (size_t)BDIM * LDIM * LDIM;
    const size_t base = ((size_t)batch * LDIM + row) * LDIM;
    for (int jv = tid; jv < 900; jv += 256) {
        h4v hv = prow[jv]; float4 b = b4[jv]; float4 c = c4[jv]; float4 cM = m4[jv];
        float4 cmv, cfv, skv;
        {
            float p = (float)hv[0]; float cm = (p * p) / (Rr * c.x);
            cmv.x = cm; cfv.x = (cm == rM && cm == cM.x) ? cm : 0.f; skv.x = p * as * b.x;
        }
        {
            float p = (float)hv[1]; float cm = (p * p) / (Rr * c.y);
            cmv.y = cm; cfv.y = (cm == rM && cm == cM.y) ? cm : 0.f; skv.y = p * as * b.y;
        }
        {
            float p = (float)hv[2]; float cm = (p * p) / (Rr * c.z);
            cmv.z = cm; cfv.z = (cm == rM && cm == cM.z) ? cm : 0.f; skv.z = p * as * b.z;
        }
        {
            float p = (float)hv[3]; float cm = (p * p) / (Rr * c.w);
            cmv.w = cm; cfv.w = (cm == rM && cm == cM.w) ? cm : 0.f; skv.w = p * as * b.w;
        }
        *(float4*)(out + base + jv * 4) = cmv;
        *(float4*)(out + PLANE + base + jv * 4) = cfv;
        *(float4*)(out + 2 * PLANE + base + jv * 4) = skv;
    }
}

extern "C" void kernel_launch(void* const* d_in, const int* in_sizes, int n_in,
                              void* d_out, int out_size, void* d_ws, size_t ws_size,
                              hipStream_t stream)
{
    const float* m0 = (const float*)d_in[0];
    const float* m1 = (const float*)d_in[1];
    const float* alpha = (const float*)d_in[2];
    float* out = (float*)d_out;
    char* ws = (char*)d_ws;

    // ws layout (bytes), all 16B-aligned; total ~111.3 MB
    short* Qb = (short*)(ws);                         //  3,686,400  bf16 mdesc0
    short* Rb = (short*)(ws + 3686400);               //  3,686,400  bf16 mdesc1
    _Float16* P  = (_Float16*)(ws + 7372800);         // 51,840,000  exp(sim)
    _Float16* PT = (_Float16*)(ws + 59212800);        // 51,840,000  exp(sim)^T
    float* vec = (float*)(ws + 111052800);            // vectors, stride VS per batch
    float* Rv   = vec;                                // row sums of P   [2*VS]
    float* Cv   = vec + 2 * VS;                       // col sums of P   [2*VS]
    float* av   = vec + 4 * VS;                       // exp(u)          [2*VS]
    float* bv   = vec + 6 * VS;                       // exp(v)          [2*VS]
    float* colM = vec + 8 * VS;                       // colwise max of cm

    hipMemsetAsync(Rv, 0, 4 * VS * sizeof(float), stream);   // Rv + Cv
    convert_kernel<<<1800, 256, 0, stream>>>((const float4*)m0, (const float4*)m1,
                                             (short4*)Qb, (short4*)Rb);
    exp_gemm_kernel<<<dim3(29, 29, 2), 256, 0, stream>>>(Qb, Rb, P, PT, Rv, Cv);

    // Sinkhorn T=3 (exp domain): u1 analytic from Rv; v1(+colM); u2; v2; u3 in final.
    u1_kernel<<<dim3(15, 2), 256, 0, stream>>>(Rv, av, alpha);
    skh_kernel<<<dim3(901, 2), 256, 0, stream>>>(PT, av, bv, alpha, Cv, Rv, colM);
    skh_kernel<<<dim3(901, 2), 256, 0, stream>>>(P, bv, av, alpha, nullptr, nullptr, nullptr);
    skh_kernel<<<dim3(901, 2), 256, 0, stream>>>(PT, av, bv, alpha, nullptr, nullptr, nullptr);

    final_kernel<<<dim3(3600, 2), 256, 0, stream>>>(P, bv, Rv, Cv, colM, alpha, out);
}